// Round 2
// baseline (1012.354 us; speedup 1.0000x reference)
//
#include <hip/hip_runtime.h>
#include <math.h>

#define SDIM 1024
#define DDIM 512
#define NRBF 8
#define FEAT 20

// clang-native float4 (works with __builtin_nontemporal_load/store,
// same 16B layout and dwordx4 codegen as HIP's float4).
typedef float f4 __attribute__((ext_vector_type(4)));

__global__ void __launch_bounds__(256, 4) corr_node_kernel(
    const float* __restrict__ x, const float* __restrict__ Cmat,
    const unsigned char* __restrict__ mask,
    const float* __restrict__ W, const float* __restrict__ bias,
    const float* __restrict__ gamma, const float* __restrict__ beta,
    const float* __restrict__ gatep,
    const float* __restrict__ centers, const float* __restrict__ widths,
    float* __restrict__ out, int nrows)
{
  __shared__ float Wl[FEAT * DDIM];  // 40 KB -> 4 blocks/CU (16 waves/CU)

  const int tid = threadIdx.x;
  // Stage W (20x512 f32) into LDS, contiguous float4 copy (10 iters/thread).
  {
    const f4* Wg = (const f4*)W;
    f4* Wd = (f4*)Wl;
#pragma unroll
    for (int i = 0; i < (FEAT * DDIM / 4) / 256; ++i)
      Wd[i * 256 + tid] = Wg[i * 256 + tid];
  }

  const float gate = gatep[0];
  // centers/widths are wave-uniform loop invariants -> scalar loads / SGPRs.
  float cen[NRBF], iwid[NRBF];
#pragma unroll
  for (int j = 0; j < NRBF; ++j) {
    cen[j] = centers[j];
    iwid[j] = 1.0f / (widths[j] + 1e-6f);
  }

  const int lane = tid & 63;
  const int wv = tid >> 6;
  const int gw = blockIdx.x * 4 + wv;
  const int nw = gridDim.x * 4;

  // Per-lane persistent params for this lane's 8 dims: {4*lane..+3, 256+4*lane..+3}
  const f4* g4 = (const f4*)gamma;
  const f4* b4 = (const f4*)beta;
  const f4* pb4 = (const f4*)bias;
  const f4 ga0 = g4[lane], ga1 = g4[64 + lane];
  const f4 be0 = b4[lane], be1 = b4[64 + lane];
  const f4 pb0 = pb4[lane], pb1 = pb4[64 + lane];

  __syncthreads();  // W staged; no further barriers

  const f4* Wl4 = (const f4*)Wl;

  if (gw >= nrows) return;  // (after the barrier; grid is 4096 waves << nrows)

  // ---- prologue: load first C row (16 f32/lane as 4x float4, coalesced) ----
  int row = gw;
  f4 cv[4];
  {
    const f4* crow = (const f4*)(Cmat + (size_t)row * SDIM);
#pragma unroll
    for (int j = 0; j < 4; ++j)
      cv[j] = __builtin_nontemporal_load(&crow[j * 64 + lane]);
  }

  for (;;) {
    const int nrow = row + nw;
    const bool more = (nrow < nrows);

    // ---- prefetch NEXT row's C while we chew on the current one ----
    const f4* cnx = (const f4*)(Cmat + (size_t)(more ? nrow : row) * SDIM);
    f4 pv[4];
#pragma unroll
    for (int j = 0; j < 4; ++j)
      pv[j] = __builtin_nontemporal_load(&cnx[j * 64 + lane]);

    // ---- single-pass stats: sum, sum-of-squares, max, min ----
    float s = 0.f, s2 = 0.f, mx = -1e30f, mn = 1e30f;
#pragma unroll
    for (int j = 0; j < 4; ++j) {
#pragma unroll
      for (int q = 0; q < 4; ++q) {
        const float c = fminf(fmaxf(cv[j][q], 0.f), 1.f);
        s += c;
        s2 = fmaf(c, c, s2);
        mx = fmaxf(mx, c);
        mn = fminf(mn, c);
      }
    }
    // one interleaved 6-step butterfly: 4 independent DS ops per step pipeline
#pragma unroll
    for (int off = 32; off > 0; off >>= 1) {
      s  += __shfl_xor(s, off, 64);
      s2 += __shfl_xor(s2, off, 64);
      mx = fmaxf(mx, __shfl_xor(mx, off, 64));
      mn = fminf(mn, __shfl_xor(mn, off, 64));
    }
    const float mean = s * (1.0f / SDIM);
    const float cvar = s2 * (1.0f / SDIM) - mean * mean;
    const float sd = sqrtf(fmaxf(cvar, 0.f));

    // ---- 20-dim feature vector (all lanes redundantly; trivial VALU) ----
    float z[FEAT];
    z[0] = mean; z[1] = mx; z[2] = mn; z[3] = sd;
#pragma unroll
    for (int j = 0; j < NRBF; ++j) {
      const float dm = (mean - cen[j]) * iwid[j];
      const float dx = (mx - cen[j]) * iwid[j];
      z[4 + j]  = __expf(-0.5f * dm * dm);
      z[12 + j] = __expf(-0.5f * dx * dx);
    }

    // ---- pe = z @ W + b for this lane's 8 dims (LDS ds_read_b128 stream) ----
    f4 pe0 = pb0, pe1 = pb1;
#pragma unroll
    for (int k = 0; k < FEAT; ++k) {
      const float zk = z[k];
      const f4 w0 = Wl4[k * 128 + lane];
      const f4 w1 = Wl4[k * 128 + 64 + lane];
      pe0.x = fmaf(zk, w0.x, pe0.x); pe0.y = fmaf(zk, w0.y, pe0.y);
      pe0.z = fmaf(zk, w0.z, pe0.z); pe0.w = fmaf(zk, w0.w, pe0.w);
      pe1.x = fmaf(zk, w1.x, pe1.x); pe1.y = fmaf(zk, w1.y, pe1.y);
      pe1.z = fmaf(zk, w1.z, pe1.z); pe1.w = fmaf(zk, w1.w, pe1.w);
    }

    // ---- x load issued here: LN reduce chain below covers its latency ----
    const f4* xr = (const f4*)(x + (size_t)row * DDIM);
    const f4 x0 = __builtin_nontemporal_load(&xr[lane]);
    const f4 x1 = __builtin_nontemporal_load(&xr[64 + lane]);

    // ---- LayerNorm via moments: one interleaved 2-chain butterfly ----
    float ps = pe0.x + pe0.y + pe0.z + pe0.w + pe1.x + pe1.y + pe1.z + pe1.w;
    float pq = pe0.x * pe0.x;
    pq = fmaf(pe0.y, pe0.y, pq); pq = fmaf(pe0.z, pe0.z, pq);
    pq = fmaf(pe0.w, pe0.w, pq); pq = fmaf(pe1.x, pe1.x, pq);
    pq = fmaf(pe1.y, pe1.y, pq); pq = fmaf(pe1.z, pe1.z, pq);
    pq = fmaf(pe1.w, pe1.w, pq);
#pragma unroll
    for (int off = 32; off > 0; off >>= 1) {
      ps += __shfl_xor(ps, off, 64);
      pq += __shfl_xor(pq, off, 64);
    }
    const float mu = ps * (1.0f / DDIM);
    const float lvar = pq * (1.0f / DDIM) - mu * mu;
    const float rstd = rsqrtf(fmaxf(lvar, 0.f) + 1e-5f);

    const float keep = mask[row] ? 0.0f : gate;  // masked -> pe contributes 0

    // ---- epilogue: out = x + keep * (norm(pe)*gamma + beta), coalesced f4 ----
    f4* orow = (f4*)(out + (size_t)row * DDIM);
    f4 o0, o1;
    o0.x = x0.x + keep * ((pe0.x - mu) * rstd * ga0.x + be0.x);
    o0.y = x0.y + keep * ((pe0.y - mu) * rstd * ga0.y + be0.y);
    o0.z = x0.z + keep * ((pe0.z - mu) * rstd * ga0.z + be0.z);
    o0.w = x0.w + keep * ((pe0.w - mu) * rstd * ga0.w + be0.w);
    o1.x = x1.x + keep * ((pe1.x - mu) * rstd * ga1.x + be1.x);
    o1.y = x1.y + keep * ((pe1.y - mu) * rstd * ga1.y + be1.y);
    o1.z = x1.z + keep * ((pe1.z - mu) * rstd * ga1.z + be1.z);
    o1.w = x1.w + keep * ((pe1.w - mu) * rstd * ga1.w + be1.w);
    __builtin_nontemporal_store(o0, &orow[lane]);
    __builtin_nontemporal_store(o1, &orow[64 + lane]);

    if (!more) break;
    row = nrow;
    cv[0] = pv[0]; cv[1] = pv[1]; cv[2] = pv[2]; cv[3] = pv[3];
  }
}

extern "C" void kernel_launch(void* const* d_in, const int* in_sizes, int n_in,
                              void* d_out, int out_size, void* d_ws, size_t ws_size,
                              hipStream_t stream) {
  const float* x = (const float*)d_in[0];
  const float* Cmat = (const float*)d_in[1];
  const unsigned char* mask = (const unsigned char*)d_in[2];
  const float* W = (const float*)d_in[3];
  const float* bias = (const float*)d_in[4];
  const float* gamma = (const float*)d_in[5];
  const float* beta = (const float*)d_in[6];
  const float* gate = (const float*)d_in[7];
  const float* centers = (const float*)d_in[8];
  const float* widths = (const float*)d_in[9];
  float* out = (float*)d_out;

  const int nrows = in_sizes[0] / DDIM;  // 100000

  // 1024 blocks x 256 threads: 4 blocks/CU (40KB LDS each), fully resident,
  // grid-stride over rows with one wave per row, next-row C prefetched.
  corr_node_kernel<<<1024, 256, 0, stream>>>(
      x, Cmat, mask, W, bias, gamma, beta, gate, centers, widths, out, nrows);
}